// Round 9
// baseline (2761.193 us; speedup 1.0000x reference)
//
#include <hip/hip_runtime.h>
#include <cstdint>

typedef _Float16 f16;
typedef _Float16 f16x4 __attribute__((ext_vector_type(4)));
typedef _Float16 f16x8 __attribute__((ext_vector_type(8)));
typedef float    f32x4 __attribute__((ext_vector_type(4)));

#define BATCH 8
#define NSEQ  1800
#define DIM   512
#define NMASK 900
#define MROWS 14400   // BATCH*NSEQ

__device__ __forceinline__ float gelu_f(float x) {
  // tanh-approx gelu (jax.nn.gelu approximate=True)
  float x3 = x * x * x;
  float y  = 0.7978845608028654f * (x + 0.044715f * x3);
  float t;
  if (y > 15.f)       t = 1.f;
  else if (y < -15.f) t = -1.f;
  else { float e = __expf(2.f * y); t = (e - 1.f) / (e + 1.f); }
  return 0.5f * x * (1.f + t);
}

// ---------------- mask scatter ----------------
__global__ void scatter_mask(const int* __restrict__ mi, int* __restrict__ maskf) {
  int i = blockIdx.x * 256 + threadIdx.x;
  if (i < BATCH * NMASK) {
    int b = i / NMASK;
    maskf[b * NSEQ + mi[i]] = 1;
  }
}

// ---------------- weight transpose + f16 convert: in[K,N] -> out[N,K] ----------------
__global__ void transposeW(const float* __restrict__ in, f16* __restrict__ out, int K, int N) {
  long off = (long)blockIdx.z * K * N;
  const float* ip = in + off;
  f16* op = out + off;
  __shared__ float tile[32][33];
  int n0 = blockIdx.x * 32, k0 = blockIdx.y * 32;
  int tx = threadIdx.x, ty = threadIdx.y;  // (32,8)
#pragma unroll
  for (int i = 0; i < 4; ++i)
    tile[ty + 8 * i][tx] = ip[(long)(k0 + ty + 8 * i) * N + n0 + tx];
  __syncthreads();
#pragma unroll
  for (int i = 0; i < 4; ++i)
    op[(long)(n0 + ty + 8 * i) * K + k0 + tx] = (f16)tile[tx][ty + 8 * i];
}

// ---------------- V transpose per layer: qkv[:,1024:1536] -> Vt[(b*8+h)*64+dh][1800] ----------------
__global__ __launch_bounds__(256)
void transposeV(const f16* __restrict__ qkv, f16* __restrict__ Vt) {
  __shared__ f16 tl[64][72];
  const int kt = blockIdx.x, bh = blockIdx.y;     // (29, 64)
  const int b = bh >> 3, hh = bh & 7;
  const int k0 = kt * 64;
  const int t = threadIdx.x;
  const int r = t >> 3, c = t & 7;
  const f16* src = qkv + (long)b * NSEQ * 1536 + hh * 64 + 1024;
  int key0 = k0 + r;      if (key0 > NSEQ - 1) key0 = NSEQ - 1;
  int key1 = k0 + r + 32; if (key1 > NSEQ - 1) key1 = NSEQ - 1;
  *(uint4*)&tl[r][c * 8]      = *(const uint4*)(src + (long)key0 * 1536 + c * 8);
  *(uint4*)&tl[r + 32][c * 8] = *(const uint4*)(src + (long)key1 * 1536 + c * 8);
  __syncthreads();
  f16* dst = Vt + (long)bh * 64 * 1800;
  const int dh = t & 63;
#pragma unroll
  for (int it = 0; it < 2; ++it) {
    int kc = (t >> 6) + it * 4;        // 0..7
    if (k0 + kc * 8 < NSEQ) {          // 1800 % 8 == 0
      f16x8 v;
#pragma unroll
      for (int j = 0; j < 8; ++j) v[j] = tl[kc * 8 + j][dh];
      *(f16x8*)(dst + (long)dh * 1800 + k0 + kc * 8) = v;
    }
  }
}

// ---------------- patch embed + pos/val emb + mask token -> x0 ----------------
__global__ __launch_bounds__(256)
void prep_kernel(const float* __restrict__ img, const float* __restrict__ pos_table,
                 const float* __restrict__ val_table, const float* __restrict__ patch_W,
                 const float* __restrict__ patch_b, const float* __restrict__ mask_tok,
                 const int* __restrict__ valid_len, const int* __restrict__ maskf,
                 float* __restrict__ patches, float* __restrict__ x0) {
  int n = blockIdx.x;       // 0..1799
  int b = blockIdx.y;       // 0..7
  int t = threadIdx.x;
  __shared__ float p[6];
  int h = n / 75, ws = n % 75;
  if (t < 6) {
    int pp = t / 3, c = t % 3;
    float v = img[((b * 3 + c) * 24 + h) * 150 + ws * 2 + pp];
    p[t] = v;
    patches[((long)b * NSEQ + n) * 6 + t] = v;
  }
  __syncthreads();
  int vl = valid_len[b];
  if (vl == 150) vl = 149;
  int nv = (vl + 1) >> 1;          // ceil(vl/2)
  int seg = (ws < nv) ? 1 : 0;
  bool masked = maskf[b * NSEQ + n] != 0;
  for (int d = t; d < DIM; d += 256) {
    float pos = pos_table[(long)(n + 1) * DIM + d] + val_table[seg * DIM + d];
    float v;
    if (masked) {
      v = mask_tok[d] + pos;
    } else {
      float acc = patch_b[d] + pos;
#pragma unroll
      for (int j = 0; j < 6; ++j) acc += p[j] * patch_W[j * DIM + d];
      v = acc;
    }
    x0[((long)b * NSEQ + n) * DIM + d] = v;
  }
}

// ---------------- LayerNorm (fp32 in -> f16 out) ----------------
__global__ __launch_bounds__(256)
void ln_kernel(const float* __restrict__ x, const float* __restrict__ s,
               const float* __restrict__ bb, f16* __restrict__ out) {
  long row = blockIdx.x;
  const float* xr = x + row * DIM;
  int t = threadIdx.x;
  float v0 = xr[t], v1 = xr[t + 256];
  float sum = v0 + v1, sq = v0 * v0 + v1 * v1;
#pragma unroll
  for (int mk = 1; mk < 64; mk <<= 1) {
    sum += __shfl_xor(sum, mk);
    sq  += __shfl_xor(sq, mk);
  }
  __shared__ float red[8];
  int wave = t >> 6, lane = t & 63;
  if (lane == 0) { red[wave] = sum; red[wave + 4] = sq; }
  __syncthreads();
  sum = red[0] + red[1] + red[2] + red[3];
  sq  = red[4] + red[5] + red[6] + red[7];
  float mean = sum * (1.f / DIM);
  float var  = sq * (1.f / DIM) - mean * mean;
  float rstd = rsqrtf(var + 1e-5f);
  out[row * DIM + t]       = (f16)((v0 - mean) * rstd * s[t] + bb[t]);
  out[row * DIM + t + 256] = (f16)((v1 - mean) * rstd * s[t + 256] + bb[t + 256]);
}

// ---------------- MFMA f16 GEMM v3: BK=64, swapped operands, reg-prefetch pipeline ----------------
// Prefetch next k-tile (8x uint4/thread) into registers during current tile's MFMA
// (attn-R5 mechanism: inter-tile critical path = LDS writes, not global latency).
// mfma(a=B-frag, b=A-frag) -> D[row=n][col=m]: 4 consecutive n/thread -> float4/f16x4 stores.
template <int EPI>
__global__ __launch_bounds__(256, 4)
void gemm_kernel(const f16* __restrict__ A, const f16* __restrict__ Bt,
                 const float* __restrict__ bias, const float* __restrict__ res,
                 float* __restrict__ outF, f16* __restrict__ outH,
                 int M, int N, int K) {
  __shared__ f16x8 As[8 * 128];   // [k-chunk(8)][row(128)] 16B units
  __shared__ f16x8 Bs[8 * 128];
  const int tid  = threadIdx.x;
  const int wave = tid >> 6, lane = tid & 63;
  const int quad = lane >> 4, l16 = lane & 15;
  const int wm = wave >> 1, wn = wave & 1;
  const long rowBase = (long)blockIdx.y * 128;
  const long colBase = (long)blockIdx.x * 128;

  f32x4 acc[4][4];   // [ni][mi]
  f32x4 zero = {0.f, 0.f, 0.f, 0.f};
#pragma unroll
  for (int ni = 0; ni < 4; ++ni)
#pragma unroll
    for (int mi = 0; mi < 4; ++mi) acc[ni][mi] = zero;

  long rA0 = rowBase + lane;       if (rA0 > M - 1) rA0 = M - 1;
  long rA1 = rowBase + 64 + lane;  if (rA1 > M - 1) rA1 = M - 1;
  const f16* Arow0 = A + rA0 * K + wave * 8;    // chunk c = wave (k-offset wave*8)
  const f16* Arow1 = A + rA1 * K + wave * 8;
  const f16* Brow0 = Bt + (colBase + lane) * K + wave * 8;
  const f16* Brow1 = Bt + (colBase + 64 + lane) * K + wave * 8;
  uint4* AsC0 = (uint4*)As + wave * 128;         // c=wave,   rows 0-63 (+lane)
  uint4* AsC1 = AsC0 + 64;
  uint4* AsC2 = (uint4*)As + (wave + 4) * 128;   // c=wave+4
  uint4* AsC3 = AsC2 + 64;
  uint4* BsC0 = (uint4*)Bs + wave * 128;
  uint4* BsC1 = BsC0 + 64;
  uint4* BsC2 = (uint4*)Bs + (wave + 4) * 128;
  uint4* BsC3 = BsC2 + 64;

  // prefetch tile 0
  uint4 pa0 = *(const uint4*)(Arow0);
  uint4 pa1 = *(const uint4*)(Arow1);
  uint4 pa2 = *(const uint4*)(Arow0 + 32);
  uint4 pa3 = *(const uint4*)(Arow1 + 32);
  uint4 pb0 = *(const uint4*)(Brow0);
  uint4 pb1 = *(const uint4*)(Brow1);
  uint4 pb2 = *(const uint4*)(Brow0 + 32);
  uint4 pb3 = *(const uint4*)(Brow1 + 32);

  for (int kt = 0; kt < K; kt += 64) {
    __syncthreads();                 // consumers of previous tile done
    AsC0[lane] = pa0;
    AsC1[lane] = pa1;
    AsC2[lane] = pa2;
    AsC3[lane] = pa3;
    BsC0[lane] = pb0;
    BsC1[lane] = pb1;
    BsC2[lane] = pb2;
    BsC3[lane] = pb3;
    if (kt + 64 < K) {               // prefetch next tile (overlaps MFMA below)
      int ko = kt + 64;
      pa0 = *(const uint4*)(Arow0 + ko);
      pa1 = *(const uint4*)(Arow1 + ko);
      pa2 = *(const uint4*)(Arow0 + ko + 32);
      pa3 = *(const uint4*)(Arow1 + ko + 32);
      pb0 = *(const uint4*)(Brow0 + ko);
      pb1 = *(const uint4*)(Brow1 + ko);
      pb2 = *(const uint4*)(Brow0 + ko + 32);
      pb3 = *(const uint4*)(Brow1 + ko + 32);
    }
    __syncthreads();                 // tile staged
#pragma unroll
    for (int ks = 0; ks < 2; ++ks) {
      f16x8 af[4], bf[4];
#pragma unroll
      for (int mi = 0; mi < 4; ++mi) af[mi] = As[(ks * 4 + quad) * 128 + wm * 64 + mi * 16 + l16];
#pragma unroll
      for (int ni = 0; ni < 4; ++ni) bf[ni] = Bs[(ks * 4 + quad) * 128 + wn * 64 + ni * 16 + l16];
#pragma unroll
      for (int ni = 0; ni < 4; ++ni)
#pragma unroll
        for (int mi = 0; mi < 4; ++mi)
          acc[ni][mi] = __builtin_amdgcn_mfma_f32_16x16x32_f16(bf[ni], af[mi], acc[ni][mi], 0, 0, 0);
    }
  }

  // epilogue: m = rowBase + wm*64 + mi*16 + l16 ; n = colBase + wn*64 + ni*16 + quad*4 + r
#pragma unroll
  for (int mi = 0; mi < 4; ++mi) {
    long m = rowBase + wm * 64 + mi * 16 + l16;
    if (m < M) {
#pragma unroll
      for (int ni = 0; ni < 4; ++ni) {
        long n = colBase + wn * 64 + ni * 16 + quad * 4;
        float4 bv = *(const float4*)&bias[n];
        f32x4 v = acc[ni][mi];
        v[0] += bv.x; v[1] += bv.y; v[2] += bv.z; v[3] += bv.w;
        long o = m * N + n;
        if (EPI == 1) {
          float4 rr = *(const float4*)&res[o];
          float4 ov = {v[0] + rr.x, v[1] + rr.y, v[2] + rr.z, v[3] + rr.w};
          *(float4*)&outF[o] = ov;
        } else if (EPI == 2) {
          f16x4 hv;
#pragma unroll
          for (int r = 0; r < 4; ++r) hv[r] = (f16)gelu_f(v[r]);
          *(f16x4*)&outH[o] = hv;
        } else {
          f16x4 hv;
#pragma unroll
          for (int r = 0; r < 4; ++r) hv[r] = (f16)v[r];
          *(f16x4*)&outH[o] = hv;
        }
      }
    }
  }
}

// ---------------- MFMA flash attention v6: last-tile mask peeled ----------------
__global__ __launch_bounds__(256, 4)
void attn_kernel(const f16* __restrict__ qkv, const f16* __restrict__ Vt,
                 f16* __restrict__ out) {
  const int g = blockIdx.x;                  // 0..959
  const int hi = g / 120, rem = g % 120;     // 120 = 15 q-tiles * 8
  const int qt = rem >> 3;                   // 0..14
  const int bh = hi * 8 + (rem & 7);         // g%8 == bh&7 -> one XCD per bh
  const int b = bh >> 3, hh = bh & 7;
  const int t = threadIdx.x;
  const int wave = t >> 6, lane = t & 63;
  const int quad = lane >> 4, l16 = lane & 15;
  const int q0 = qt * 128;
  const long baseBN = (long)b * NSEQ;
  const float K1 = 0.18033688011112042f;     // 0.125 * log2(e)

  __shared__ f16 Ks[64][80];   // [key][dh]
  __shared__ f16 Vs[64][80];   // [dh][key]
  __shared__ f16 Ps[64][80];   // [q%64][key], rows wave-private, reused A->B

  int qrA = q0 + wave * 32 + l16;      if (qrA > NSEQ - 1) qrA = NSEQ - 1;
  int qrB = q0 + wave * 32 + 16 + l16; if (qrB > NSEQ - 1) qrB = NSEQ - 1;
  const f16* QpA = qkv + (baseBN + qrA) * 1536 + hh * 64 + quad * 8;
  const f16* QpB = qkv + (baseBN + qrB) * 1536 + hh * 64 + quad * 8;
  f16x8 qfA0 = *(const f16x8*)(QpA);
  f16x8 qfA1 = *(const f16x8*)(QpA + 32);
  f16x8 qfB0 = *(const f16x8*)(QpB);
  f16x8 qfB1 = *(const f16x8*)(QpB + 32);

  f32x4 oA[4], oB[4];
  float lsA[4] = {0.f, 0.f, 0.f, 0.f}, lsB[4] = {0.f, 0.f, 0.f, 0.f};
#pragma unroll
  for (int nt = 0; nt < 4; ++nt) { oA[nt] = f32x4{0,0,0,0}; oB[nt] = f32x4{0,0,0,0}; }

  const f16* Kg = qkv + baseBN * 1536 + hh * 64 + 512;
  const f16* Vg = Vt + (long)bh * 64 * 1800;
  const int sr = t >> 3, sc = t & 7;
  const uint4 z4 = {0u, 0u, 0u, 0u};

  const f16* KgS = Kg + (long)sr * 1536 + sc * 8;
  const f16* VgS = Vg + (long)sr * 1800 + sc * 8;

  uint4 pk0 = *(const uint4*)(KgS);
  uint4 pk1 = *(const uint4*)(KgS + (long)32 * 1536);
  uint4 pv0 = *(const uint4*)(VgS);
  uint4 pv1 = *(const uint4*)(VgS + (long)32 * 1800);

  // per-tile compute; MASK specializes at the two literal call sites (constprop)
  auto tile_compute = [&](const bool MASK) {
    // ---- group A ----
#pragma unroll
    for (int n = 0; n < 4; ++n) {
      f16x8 b0 = *(const f16x8*)&Ks[n * 16 + l16][quad * 8];
      f16x8 b1 = *(const f16x8*)&Ks[n * 16 + l16][32 + quad * 8];
      f32x4 zz = {0.f, 0.f, 0.f, 0.f};
      zz = __builtin_amdgcn_mfma_f32_16x16x32_f16(qfA0, b0, zz, 0, 0, 0);
      zz = __builtin_amdgcn_mfma_f32_16x16x32_f16(qfA1, b1, zz, 0, 0, 0);
      bool bad = MASK && (n > 0 || l16 >= 8);
#pragma unroll
      for (int r = 0; r < 4; ++r) {
        float pp = exp2f(fmaf(zz[r], K1, -8.f));
        if (bad) pp = 0.f;
        Ps[wave * 16 + quad * 4 + r][n * 16 + l16] = (f16)pp;
        lsA[r] += pp;
      }
    }
    {
      f16x8 pa0 = *(const f16x8*)&Ps[wave * 16 + l16][quad * 8];
      f16x8 pa1 = *(const f16x8*)&Ps[wave * 16 + l16][32 + quad * 8];
#pragma unroll
      for (int nt = 0; nt < 4; ++nt) {
        f16x8 vb0 = *(const f16x8*)&Vs[nt * 16 + l16][quad * 8];
        f16x8 vb1 = *(const f16x8*)&Vs[nt * 16 + l16][32 + quad * 8];
        oA[nt] = __builtin_amdgcn_mfma_f32_16x16x32_f16(pa0, vb0, oA[nt], 0, 0, 0);
        oA[nt] = __builtin_amdgcn_mfma_f32_16x16x32_f16(pa1, vb1, oA[nt], 0, 0, 0);
      }
    }
    // ---- group B (reuses Ps rows; same-wave DS ordering -> WAR safe) ----
#pragma unroll
    for (int n = 0; n < 4; ++n) {
      f16x8 b0 = *(const f16x8*)&Ks[n * 16 + l16][quad * 8];
      f16x8 b1 = *(const f16x8*)&Ks[n * 16 + l16][32 + quad * 8];
      f32x4 zz = {0.f, 0.f, 0.f, 0.f};
      zz = __builtin_amdgcn_mfma_f32_16x16x32_f16(qfB0, b0, zz, 0, 0, 0);
      zz = __builtin_amdgcn_mfma_f32_16x16x32_f16(qfB1, b1, zz, 0, 0, 0);
      bool bad = MASK && (n > 0 || l16 >= 8);
#pragma unroll
      for (int r = 0; r < 4; ++r) {
        float pp = exp2f(fmaf(zz[r], K1, -8.f));
        if (bad) pp = 0.f;
        Ps[wave * 16 + quad * 4 + r][n * 16 + l16] = (f16)pp;
        lsB[r] += pp;
      }
    }
    {
      f16x8 pa0 = *(const f16x8*)&Ps[wave * 16 + l16][quad * 8];
      f16x8 pa1 = *(const f16x8*)&Ps[wave * 16 + l16][32 + quad * 8];
#pragma unroll
      for (int nt = 0; nt < 4; ++nt) {
        f16x8 vb0 = *(const f16x8*)&Vs[nt * 16 + l16][quad * 8];
        f16x8 vb1 = *(const f16x8*)&Vs[nt * 16 + l16][32 + quad * 8];
        oB[nt] = __builtin_amdgcn_mfma_f32_16x16x32_f16(pa0, vb0, oB[nt], 0, 0, 0);
        oB[nt] = __builtin_amdgcn_mfma_f32_16x16x32_f16(pa1, vb1, oB[nt], 0, 0, 0);
      }
    }
  };

  for (int kt = 0; kt < 28; ++kt) {          // tiles 0..27: no key masking
    __syncthreads();
    *(uint4*)&Ks[sr][sc * 8]      = pk0;
    *(uint4*)&Ks[sr + 32][sc * 8] = pk1;
    *(uint4*)&Vs[sr][sc * 8]      = pv0;
    *(uint4*)&Vs[sr + 32][sc * 8] = pv1;
    {
      long ko = (long)(kt + 1) * 64;
      pk0 = *(const uint4*)(KgS + ko * 1536);
      pk1 = *(const uint4*)(KgS + (ko + 32) * 1536);
      bool vok = (ko + sc * 8) < NSEQ;
      pv0 = vok ? *(const uint4*)(VgS + ko) : z4;
      pv1 = vok ? *(const uint4*)(VgS + (long)32 * 1800 + ko) : z4;
    }
    __syncthreads();
    tile_compute(false);
  }
  {                                          // tile 28: mask keys >= 1800
    __syncthreads();
    *(uint4*)&Ks[sr][sc * 8]      = pk0;
    *(uint4*)&Ks[sr + 32][sc * 8] = pk1;
    *(uint4*)&Vs[sr][sc * 8]      = pv0;
    *(uint4*)&Vs[sr + 32][sc * 8] = pv1;
    __syncthreads();
    tile_compute(true);
  }

#pragma unroll
  for (int mk = 1; mk < 16; mk <<= 1)
#pragma unroll
    for (int r = 0; r < 4; ++r) {
      lsA[r] += __shfl_xor(lsA[r], mk);
      lsB[r] += __shfl_xor(lsB[r], mk);
    }

#pragma unroll
  for (int r = 0; r < 4; ++r) {
    int qgA = q0 + wave * 32 + quad * 4 + r;
    if (qgA < NSEQ) {
      float inv = 1.f / lsA[r];
#pragma unroll
      for (int nt = 0; nt < 4; ++nt)
        out[(baseBN + qgA) * 512 + hh * 64 + nt * 16 + l16] = (f16)(oA[nt][r] * inv);
    }
    int qgB = qgA + 16;
    if (qgB < NSEQ) {
      float inv = 1.f / lsB[r];
#pragma unroll
      for (int nt = 0; nt < 4; ++nt)
        out[(baseBN + qgB) * 512 + hh * 64 + nt * 16 + l16] = (f16)(oB[nt][r] * inv);
    }
  }
}

// ---------------- head: 225 blocks x 32 rows, Wt in registers, 6 atomics/block ----------------
__global__ __launch_bounds__(192)
void head_kernel(const float* __restrict__ x, const float* __restrict__ patches,
                 const int* __restrict__ mi, const float* __restrict__ Wt,
                 const float* __restrict__ bt, float* __restrict__ lossAcc) {
  int t = threadIdx.x;            // 192 = 6 pd * 32 lanes
  int pd = t / 32, sg = t % 32;
  float wt[16];
#pragma unroll
  for (int k = 0; k < 16; ++k) wt[k] = Wt[(sg * 16 + k) * 6 + pd];
  float btv = bt[pd];
  float accAll = 0.f;
  for (int rr = 0; rr < 32; ++rr) {
    int bi = blockIdx.x * 32 + rr;    // 0..7199
    int b = bi / NMASK;
    int idx = mi[bi];
    const float4* xr4 = (const float4*)(x + ((long)b * NSEQ + idx) * DIM);
    float acc = 0.f;
#pragma unroll
    for (int j = 0; j < 4; ++j) {
      float4 xa = xr4[sg * 4 + j];
      acc += xa.x * wt[j * 4] + xa.y * wt[j * 4 + 1] + xa.z * wt[j * 4 + 2] + xa.w * wt[j * 4 + 3];
    }
#pragma unroll
    for (int mk = 1; mk < 32; mk <<= 1) acc += __shfl_xor(acc, mk);
    if (sg == 0) {
      float pred = acc + btv;
      accAll += fabsf(pred - patches[((long)b * NSEQ + idx) * 6 + pd]);
    }
  }
  if (sg == 0) atomicAdd(lossAcc, accAll);
}

__global__ void finalize_kernel(const float* __restrict__ acc, float* __restrict__ out) {
  if (threadIdx.x == 0 && blockIdx.x == 0)
    out[0] = acc[0] * (1.0f / 38880000.0f);   // /(8*900*6) / 900
}

// ---------------- launcher ----------------
extern "C" void kernel_launch(void* const* d_in, const int* in_sizes, int n_in,
                              void* d_out, int out_size, void* d_ws, size_t ws_size,
                              hipStream_t stream) {
  (void)in_sizes; (void)n_in; (void)out_size; (void)ws_size;
  const float* img       = (const float*)d_in[0];
  const float* pos_table = (const float*)d_in[1];
  const float* val_table = (const float*)d_in[2];
  const float* patch_W   = (const float*)d_in[3];
  const float* patch_b   = (const float*)d_in[4];
  const float* mask_tok  = (const float*)d_in[5];
  const float* ln1_s     = (const float*)d_in[6];
  const float* ln1_b     = (const float*)d_in[7];
  const float* Wqkv      = (const float*)d_in[8];
  const float* bqkv      = (const float*)d_in[9];
  const float* Wo        = (const float*)d_in[10];
  const float* bo        = (const float*)d_in[11];
  const float* ln2_s     = (const float*)d_in[12];
  const float* ln2_b     = (const float*)d_in[13];
  const float* W1        = (const float*)d_in[14];
  const float* b1        = (const float*)d_in[15];
  const float* W2        = (const float*)d_in[16];
  const float* b2        = (const float*)d_in[17];
  const float* Wt        = (const float*)d_in[18];
  const float* bt        = (const float*)d_in[19];
  const int* valid_len   = (const int*)d_in[20];
  const int* mask_idx    = (const int*)d_in[21];

  char* p = (char*)d_ws;
  auto alloc = [&](size_t bytes) { char* r = p; p += (bytes + 511) & ~(size_t)511; return r; };
  float* patches = (float*)alloc((size_t)MROWS * 6 * 4);
  int*   maskf   = (int*)alloc((size_t)MROWS * 4);
  float* lossAcc = (float*)alloc(256);
  float* x       = (float*)alloc((size_t)MROWS * 512 * 4);
  f16*   h       = (f16*)alloc((size_t)MROWS * 512 * 2 + 512); // doubles as Vt
  f16*   qkv     = (f16*)alloc((size_t)MROWS * 2048 * 2);      // shared: qkv (1536) / mlp-hidden (2048)
  f16*   attn    = (f16*)alloc((size_t)MROWS * 512 * 2);
  f16*   WqT     = (f16*)alloc((size_t)4 * 1536 * 512 * 2);
  f16*   WoT     = (f16*)alloc((size_t)4 * 512 * 512 * 2);
  f16*   W1T     = (f16*)alloc((size_t)4 * 2048 * 512 * 2);
  f16*   W2T     = (f16*)alloc((size_t)4 * 512 * 2048 * 2);
  f16*   hid     = qkv;
  f16*   Vt      = h;   // h is dead between the QKV GEMM and ln2

  hipMemsetAsync(maskf, 0, (size_t)MROWS * 4, stream);
  hipMemsetAsync(lossAcc, 0, 4, stream);
  scatter_mask<<<29, 256, 0, stream>>>(mask_idx, maskf);

  transposeW<<<dim3(48, 16, 4), dim3(32, 8), 0, stream>>>(Wqkv, WqT, 512, 1536);
  transposeW<<<dim3(16, 16, 4), dim3(32, 8), 0, stream>>>(Wo,  WoT, 512, 512);
  transposeW<<<dim3(64, 16, 4), dim3(32, 8), 0, stream>>>(W1,  W1T, 512, 2048);
  transposeW<<<dim3(16, 64, 4), dim3(32, 8), 0, stream>>>(W2,  W2T, 2048, 512);

  prep_kernel<<<dim3(1800, 8), 256, 0, stream>>>(img, pos_table, val_table, patch_W, patch_b,
                                                 mask_tok, valid_len, maskf, patches, x);

  for (int l = 0; l < 4; ++l) {
    ln_kernel<<<MROWS, 256, 0, stream>>>(x, ln1_s + l * 512, ln1_b + l * 512, h);
    gemm_kernel<0><<<dim3(12, 113), 256, 0, stream>>>(h, WqT + (size_t)l * 1536 * 512,
                                                      bqkv + l * 1536, nullptr, nullptr, qkv,
                                                      MROWS, 1536, 512);
    transposeV<<<dim3(29, 64), 256, 0, stream>>>(qkv, Vt);
    attn_kernel<<<dim3(960), 256, 0, stream>>>(qkv, Vt, attn);
    gemm_kernel<1><<<dim3(4, 113), 256, 0, stream>>>(attn, WoT + (size_t)l * 512 * 512,
                                                     bo + l * 512, x, x, nullptr,
                                                     MROWS, 512, 512);
    ln_kernel<<<MROWS, 256, 0, stream>>>(x, ln2_s + l * 512, ln2_b + l * 512, h);
    gemm_kernel<2><<<dim3(16, 113), 256, 0, stream>>>(h, W1T + (size_t)l * 2048 * 512,
                                                      b1 + l * 2048, nullptr, nullptr, hid,
                                                      MROWS, 2048, 512);
    gemm_kernel<1><<<dim3(4, 113), 256, 0, stream>>>(hid, W2T + (size_t)l * 512 * 2048,
                                                     b2 + l * 512, x, x, nullptr,
                                                     MROWS, 512, 2048);
  }

  head_kernel<<<225, 192, 0, stream>>>(x, patches, mask_idx, Wt, bt, lossAcc);
  finalize_kernel<<<1, 64, 0, stream>>>(lossAcc, (float*)d_out);
}

// Round 10
// 1792.868 us; speedup vs baseline: 1.5401x; 1.5401x over previous
//
#include <hip/hip_runtime.h>
#include <cstdint>

typedef _Float16 f16;
typedef _Float16 f16x4 __attribute__((ext_vector_type(4)));
typedef _Float16 f16x8 __attribute__((ext_vector_type(8)));
typedef float    f32x4 __attribute__((ext_vector_type(4)));

#define BATCH 8
#define NSEQ  1800
#define DIM   512
#define NMASK 900
#define MROWS 14400   // BATCH*NSEQ

// ---------------- async 16B global->LDS (with fallback) ----------------
__device__ __forceinline__ void stage16(const void* g, void* lds_wave_base, int lane) {
#if __has_builtin(__builtin_amdgcn_global_load_lds)
  (void)lane;
  __builtin_amdgcn_global_load_lds((const __attribute__((address_space(1))) void*)g,
                                   (__attribute__((address_space(3))) void*)lds_wave_base,
                                   16, 0, 0);
#else
  ((uint4*)lds_wave_base)[lane] = *(const uint4*)g;
#endif
}

__device__ __forceinline__ float gelu_f(float x) {
  // tanh-approx gelu (jax.nn.gelu approximate=True)
  float x3 = x * x * x;
  float y  = 0.7978845608028654f * (x + 0.044715f * x3);
  float t;
  if (y > 15.f)       t = 1.f;
  else if (y < -15.f) t = -1.f;
  else { float e = __expf(2.f * y); t = (e - 1.f) / (e + 1.f); }
  return 0.5f * x * (1.f + t);
}

// ---------------- mask scatter ----------------
__global__ void scatter_mask(const int* __restrict__ mi, int* __restrict__ maskf) {
  int i = blockIdx.x * 256 + threadIdx.x;
  if (i < BATCH * NMASK) {
    int b = i / NMASK;
    maskf[b * NSEQ + mi[i]] = 1;
  }
}

// ---------------- weight transpose + f16 convert: in[K,N] -> out[N,K] ----------------
__global__ void transposeW(const float* __restrict__ in, f16* __restrict__ out, int K, int N) {
  long off = (long)blockIdx.z * K * N;
  const float* ip = in + off;
  f16* op = out + off;
  __shared__ float tile[32][33];
  int n0 = blockIdx.x * 32, k0 = blockIdx.y * 32;
  int tx = threadIdx.x, ty = threadIdx.y;  // (32,8)
#pragma unroll
  for (int i = 0; i < 4; ++i)
    tile[ty + 8 * i][tx] = ip[(long)(k0 + ty + 8 * i) * N + n0 + tx];
  __syncthreads();
#pragma unroll
  for (int i = 0; i < 4; ++i)
    op[(long)(n0 + ty + 8 * i) * K + k0 + tx] = (f16)tile[tx][ty + 8 * i];
}

// ---------------- V transpose per layer: qkv[:,1024:1536] -> Vt[(b*8+h)*64+dh][1800] ----------------
__global__ __launch_bounds__(256)
void transposeV(const f16* __restrict__ qkv, f16* __restrict__ Vt) {
  __shared__ f16 tl[64][72];
  const int kt = blockIdx.x, bh = blockIdx.y;     // (29, 64)
  const int b = bh >> 3, hh = bh & 7;
  const int k0 = kt * 64;
  const int t = threadIdx.x;
  const int r = t >> 3, c = t & 7;
  const f16* src = qkv + (long)b * NSEQ * 1536 + hh * 64 + 1024;
  int key0 = k0 + r;      if (key0 > NSEQ - 1) key0 = NSEQ - 1;
  int key1 = k0 + r + 32; if (key1 > NSEQ - 1) key1 = NSEQ - 1;
  *(uint4*)&tl[r][c * 8]      = *(const uint4*)(src + (long)key0 * 1536 + c * 8);
  *(uint4*)&tl[r + 32][c * 8] = *(const uint4*)(src + (long)key1 * 1536 + c * 8);
  __syncthreads();
  f16* dst = Vt + (long)bh * 64 * 1800;
  const int dh = t & 63;
#pragma unroll
  for (int it = 0; it < 2; ++it) {
    int kc = (t >> 6) + it * 4;        // 0..7
    if (k0 + kc * 8 < NSEQ) {          // 1800 % 8 == 0
      f16x8 v;
#pragma unroll
      for (int j = 0; j < 8; ++j) v[j] = tl[kc * 8 + j][dh];
      *(f16x8*)(dst + (long)dh * 1800 + k0 + kc * 8) = v;
    }
  }
}

// ---------------- patch embed + pos/val emb + mask token -> x0 ----------------
__global__ __launch_bounds__(256)
void prep_kernel(const float* __restrict__ img, const float* __restrict__ pos_table,
                 const float* __restrict__ val_table, const float* __restrict__ patch_W,
                 const float* __restrict__ patch_b, const float* __restrict__ mask_tok,
                 const int* __restrict__ valid_len, const int* __restrict__ maskf,
                 float* __restrict__ patches, float* __restrict__ x0) {
  int n = blockIdx.x;       // 0..1799
  int b = blockIdx.y;       // 0..7
  int t = threadIdx.x;
  __shared__ float p[6];
  int h = n / 75, ws = n % 75;
  if (t < 6) {
    int pp = t / 3, c = t % 3;
    float v = img[((b * 3 + c) * 24 + h) * 150 + ws * 2 + pp];
    p[t] = v;
    patches[((long)b * NSEQ + n) * 6 + t] = v;
  }
  __syncthreads();
  int vl = valid_len[b];
  if (vl == 150) vl = 149;
  int nv = (vl + 1) >> 1;          // ceil(vl/2)
  int seg = (ws < nv) ? 1 : 0;
  bool masked = maskf[b * NSEQ + n] != 0;
  for (int d = t; d < DIM; d += 256) {
    float pos = pos_table[(long)(n + 1) * DIM + d] + val_table[seg * DIM + d];
    float v;
    if (masked) {
      v = mask_tok[d] + pos;
    } else {
      float acc = patch_b[d] + pos;
#pragma unroll
      for (int j = 0; j < 6; ++j) acc += p[j] * patch_W[j * DIM + d];
      v = acc;
    }
    x0[((long)b * NSEQ + n) * DIM + d] = v;
  }
}

// ---------------- LayerNorm (fp32 in -> f16 out) ----------------
__global__ __launch_bounds__(256)
void ln_kernel(const float* __restrict__ x, const float* __restrict__ s,
               const float* __restrict__ bb, f16* __restrict__ out) {
  long row = blockIdx.x;
  const float* xr = x + row * DIM;
  int t = threadIdx.x;
  float v0 = xr[t], v1 = xr[t + 256];
  float sum = v0 + v1, sq = v0 * v0 + v1 * v1;
#pragma unroll
  for (int mk = 1; mk < 64; mk <<= 1) {
    sum += __shfl_xor(sum, mk);
    sq  += __shfl_xor(sq, mk);
  }
  __shared__ float red[8];
  int wave = t >> 6, lane = t & 63;
  if (lane == 0) { red[wave] = sum; red[wave + 4] = sq; }
  __syncthreads();
  sum = red[0] + red[1] + red[2] + red[3];
  sq  = red[4] + red[5] + red[6] + red[7];
  float mean = sum * (1.f / DIM);
  float var  = sq * (1.f / DIM) - mean * mean;
  float rstd = rsqrtf(var + 1e-5f);
  out[row * DIM + t]       = (f16)((v0 - mean) * rstd * s[t] + bb[t]);
  out[row * DIM + t + 256] = (f16)((v1 - mean) * rstd * s[t + 256] + bb[t + 256]);
}

// ---------------- MFMA f16 GEMM v2 (R8 known-good): BK=64, swapped operands ----------------
// mfma(a=B-frag, b=A-frag) -> D[row=n][col=m]: 4 consecutive n/thread -> float4/f16x4 stores.
// EPI 0: bias -> f16; 1: bias + residual -> f32; 2: bias + gelu -> f16.
template <int EPI>
__global__ __launch_bounds__(256)
void gemm_kernel(const f16* __restrict__ A, const f16* __restrict__ Bt,
                 const float* __restrict__ bias, const float* __restrict__ res,
                 float* __restrict__ outF, f16* __restrict__ outH,
                 int M, int N, int K) {
  __shared__ f16x8 As[8 * 128];   // [k-chunk(8)][row(128)] 16B units
  __shared__ f16x8 Bs[8 * 128];
  const int tid  = threadIdx.x;
  const int wave = tid >> 6, lane = tid & 63;
  const int quad = lane >> 4, l16 = lane & 15;
  const int wm = wave >> 1, wn = wave & 1;
  const long rowBase = (long)blockIdx.y * 128;
  const long colBase = (long)blockIdx.x * 128;

  f32x4 acc[4][4];   // [ni][mi]
  f32x4 zero = {0.f, 0.f, 0.f, 0.f};
#pragma unroll
  for (int ni = 0; ni < 4; ++ni)
#pragma unroll
    for (int mi = 0; mi < 4; ++mi) acc[ni][mi] = zero;

  long rA0 = rowBase + lane;       if (rA0 > M - 1) rA0 = M - 1;
  long rA1 = rowBase + 64 + lane;  if (rA1 > M - 1) rA1 = M - 1;
  const f16* Arow0 = A + rA0 * K + wave * 8;    // chunk c = wave (k-offset wave*8)
  const f16* Arow1 = A + rA1 * K + wave * 8;
  const f16* Brow0 = Bt + (colBase + lane) * K + wave * 8;
  const f16* Brow1 = Bt + (colBase + 64 + lane) * K + wave * 8;
  char* AsC0 = (char*)As + (wave * 128) * 16;        // c=wave,   rows 0-63
  char* AsC1 = AsC0 + 64 * 16;                       // c=wave,   rows 64-127
  char* AsC2 = (char*)As + ((wave + 4) * 128) * 16;  // c=wave+4, rows 0-63
  char* AsC3 = AsC2 + 64 * 16;
  char* BsC0 = (char*)Bs + (wave * 128) * 16;
  char* BsC1 = BsC0 + 64 * 16;
  char* BsC2 = (char*)Bs + ((wave + 4) * 128) * 16;
  char* BsC3 = BsC2 + 64 * 16;

  for (int kt = 0; kt < K; kt += 64) {
    __syncthreads();
    stage16(Arow0 + kt,      AsC0, lane);
    stage16(Arow1 + kt,      AsC1, lane);
    stage16(Arow0 + kt + 32, AsC2, lane);
    stage16(Arow1 + kt + 32, AsC3, lane);
    stage16(Brow0 + kt,      BsC0, lane);
    stage16(Brow1 + kt,      BsC1, lane);
    stage16(Brow0 + kt + 32, BsC2, lane);
    stage16(Brow1 + kt + 32, BsC3, lane);
    __syncthreads();
#pragma unroll
    for (int ks = 0; ks < 2; ++ks) {
      f16x8 af[4], bf[4];
#pragma unroll
      for (int mi = 0; mi < 4; ++mi) af[mi] = As[(ks * 4 + quad) * 128 + wm * 64 + mi * 16 + l16];
#pragma unroll
      for (int ni = 0; ni < 4; ++ni) bf[ni] = Bs[(ks * 4 + quad) * 128 + wn * 64 + ni * 16 + l16];
#pragma unroll
      for (int ni = 0; ni < 4; ++ni)
#pragma unroll
        for (int mi = 0; mi < 4; ++mi)
          acc[ni][mi] = __builtin_amdgcn_mfma_f32_16x16x32_f16(bf[ni], af[mi], acc[ni][mi], 0, 0, 0);
    }
  }

  // epilogue: m = rowBase + wm*64 + mi*16 + l16 ; n = colBase + wn*64 + ni*16 + quad*4 + r
#pragma unroll
  for (int mi = 0; mi < 4; ++mi) {
    long m = rowBase + wm * 64 + mi * 16 + l16;
    if (m < M) {
#pragma unroll
      for (int ni = 0; ni < 4; ++ni) {
        long n = colBase + wn * 64 + ni * 16 + quad * 4;
        float4 bv = *(const float4*)&bias[n];
        f32x4 v = acc[ni][mi];
        v[0] += bv.x; v[1] += bv.y; v[2] += bv.z; v[3] += bv.w;
        long o = m * N + n;
        if (EPI == 1) {
          float4 rr = *(const float4*)&res[o];
          float4 ov = {v[0] + rr.x, v[1] + rr.y, v[2] + rr.z, v[3] + rr.w};
          *(float4*)&outF[o] = ov;
        } else if (EPI == 2) {
          f16x4 hv;
#pragma unroll
          for (int r = 0; r < 4; ++r) hv[r] = (f16)gelu_f(v[r]);
          *(f16x4*)&outH[o] = hv;
        } else {
          f16x4 hv;
#pragma unroll
          for (int r = 0; r < 4; ++r) hv[r] = (f16)v[r];
          *(f16x4*)&outH[o] = hv;
        }
      }
    }
  }
}

// ---------------- MFMA flash attention v6b: R8 v5b + macro-peeled last tile ----------------
// Tile body stamped via macro with LITERAL mask flag (R9's runtime-bool lambda was
// outlined by the compiler -> all state through scratch -> 556/692 MB spill traffic).
#define ATTN_TILE_BODY(MASKV)                                                           \
  {                                                                                     \
    /* ---- group A ---- */                                                             \
    _Pragma("unroll")                                                                   \
    for (int n = 0; n < 4; ++n) {                                                       \
      f16x8 b0 = *(const f16x8*)&Ks[n * 16 + l16][quad * 8];                            \
      f16x8 b1 = *(const f16x8*)&Ks[n * 16 + l16][32 + quad * 8];                       \
      f32x4 zz = {0.f, 0.f, 0.f, 0.f};                                                  \
      zz = __builtin_amdgcn_mfma_f32_16x16x32_f16(qfA0, b0, zz, 0, 0, 0);               \
      zz = __builtin_amdgcn_mfma_f32_16x16x32_f16(qfA1, b1, zz, 0, 0, 0);               \
      bool bad = (MASKV) && (n > 0 || l16 >= 8);                                        \
      _Pragma("unroll")                                                                 \
      for (int r = 0; r < 4; ++r) {                                                     \
        float pp = exp2f(fmaf(zz[r], K1, -8.f));                                        \
        if (bad) pp = 0.f;                                                              \
        Ps[wave * 16 + quad * 4 + r][n * 16 + l16] = (f16)pp;                           \
        lsA[r] += pp;                                                                   \
      }                                                                                 \
    }                                                                                   \
    {                                                                                   \
      f16x8 pa0 = *(const f16x8*)&Ps[wave * 16 + l16][quad * 8];                        \
      f16x8 pa1 = *(const f16x8*)&Ps[wave * 16 + l16][32 + quad * 8];                   \
      _Pragma("unroll")                                                                 \
      for (int nt = 0; nt < 4; ++nt) {                                                  \
        f16x8 vb0 = *(const f16x8*)&Vs[nt * 16 + l16][quad * 8];                        \
        f16x8 vb1 = *(const f16x8*)&Vs[nt * 16 + l16][32 + quad * 8];                   \
        oA[nt] = __builtin_amdgcn_mfma_f32_16x16x32_f16(pa0, vb0, oA[nt], 0, 0, 0);     \
        oA[nt] = __builtin_amdgcn_mfma_f32_16x16x32_f16(pa1, vb1, oA[nt], 0, 0, 0);     \
      }                                                                                 \
    }                                                                                   \
    /* ---- group B (reuses Ps rows; same-wave DS ordering -> WAR safe) ---- */         \
    _Pragma("unroll")                                                                   \
    for (int n = 0; n < 4; ++n) {                                                       \
      f16x8 b0 = *(const f16x8*)&Ks[n * 16 + l16][quad * 8];                            \
      f16x8 b1 = *(const f16x8*)&Ks[n * 16 + l16][32 + quad * 8];                       \
      f32x4 zz = {0.f, 0.f, 0.f, 0.f};                                                  \
      zz = __builtin_amdgcn_mfma_f32_16x16x32_f16(qfB0, b0, zz, 0, 0, 0);               \
      zz = __builtin_amdgcn_mfma_f32_16x16x32_f16(qfB1, b1, zz, 0, 0, 0);               \
      bool bad = (MASKV) && (n > 0 || l16 >= 8);                                        \
      _Pragma("unroll")                                                                 \
      for (int r = 0; r < 4; ++r) {                                                     \
        float pp = exp2f(fmaf(zz[r], K1, -8.f));                                        \
        if (bad) pp = 0.f;                                                              \
        Ps[wave * 16 + quad * 4 + r][n * 16 + l16] = (f16)pp;                           \
        lsB[r] += pp;                                                                   \
      }                                                                                 \
    }                                                                                   \
    {                                                                                   \
      f16x8 pa0 = *(const f16x8*)&Ps[wave * 16 + l16][quad * 8];                        \
      f16x8 pa1 = *(const f16x8*)&Ps[wave * 16 + l16][32 + quad * 8];                   \
      _Pragma("unroll")                                                                 \
      for (int nt = 0; nt < 4; ++nt) {                                                  \
        f16x8 vb0 = *(const f16x8*)&Vs[nt * 16 + l16][quad * 8];                        \
        f16x8 vb1 = *(const f16x8*)&Vs[nt * 16 + l16][32 + quad * 8];                   \
        oB[nt] = __builtin_amdgcn_mfma_f32_16x16x32_f16(pa0, vb0, oB[nt], 0, 0, 0);     \
        oB[nt] = __builtin_amdgcn_mfma_f32_16x16x32_f16(pa1, vb1, oB[nt], 0, 0, 0);     \
      }                                                                                 \
    }                                                                                   \
  }

__global__ __launch_bounds__(256, 4)
void attn_kernel(const f16* __restrict__ qkv, const f16* __restrict__ Vt,
                 f16* __restrict__ out) {
  const int g = blockIdx.x;                  // 0..959
  const int hi = g / 120, rem = g % 120;     // 120 = 15 q-tiles * 8
  const int qt = rem >> 3;                   // 0..14
  const int bh = hi * 8 + (rem & 7);         // g%8 == bh&7 -> one XCD per bh
  const int b = bh >> 3, hh = bh & 7;
  const int t = threadIdx.x;
  const int wave = t >> 6, lane = t & 63;
  const int quad = lane >> 4, l16 = lane & 15;
  const int q0 = qt * 128;
  const long baseBN = (long)b * NSEQ;
  const float K1 = 0.18033688011112042f;     // 0.125 * log2(e)

  __shared__ f16 Ks[64][80];   // [key][dh]
  __shared__ f16 Vs[64][80];   // [dh][key]
  __shared__ f16 Ps[64][80];   // [q%64][key], rows wave-private, reused A->B

  int qrA = q0 + wave * 32 + l16;      if (qrA > NSEQ - 1) qrA = NSEQ - 1;
  int qrB = q0 + wave * 32 + 16 + l16; if (qrB > NSEQ - 1) qrB = NSEQ - 1;
  const f16* QpA = qkv + (baseBN + qrA) * 1536 + hh * 64 + quad * 8;
  const f16* QpB = qkv + (baseBN + qrB) * 1536 + hh * 64 + quad * 8;
  f16x8 qfA0 = *(const f16x8*)(QpA);
  f16x8 qfA1 = *(const f16x8*)(QpA + 32);
  f16x8 qfB0 = *(const f16x8*)(QpB);
  f16x8 qfB1 = *(const f16x8*)(QpB + 32);

  f32x4 oA[4], oB[4];
  float lsA[4] = {0.f, 0.f, 0.f, 0.f}, lsB[4] = {0.f, 0.f, 0.f, 0.f};
#pragma unroll
  for (int nt = 0; nt < 4; ++nt) { oA[nt] = f32x4{0,0,0,0}; oB[nt] = f32x4{0,0,0,0}; }

  const f16* Kg = qkv + baseBN * 1536 + hh * 64 + 512;
  const f16* Vg = Vt + (long)bh * 64 * 1800;
  const int sr = t >> 3, sc = t & 7;
  const uint4 z4 = {0u, 0u, 0u, 0u};

  const f16* KgS = Kg + (long)sr * 1536 + sc * 8;
  const f16* VgS = Vg + (long)sr * 1800 + sc * 8;

  uint4 pk0 = *(const uint4*)(KgS);
  uint4 pk1 = *(const uint4*)(KgS + (long)32 * 1536);
  uint4 pv0 = *(const uint4*)(VgS);
  uint4 pv1 = *(const uint4*)(VgS + (long)32 * 1800);

  for (int kt = 0; kt < 28; ++kt) {          // tiles 0..27: no key masking
    __syncthreads();
    *(uint4*)&Ks[sr][sc * 8]      = pk0;
    *(uint4*)&Ks[sr + 32][sc * 8] = pk1;
    *(uint4*)&Vs[sr][sc * 8]      = pv0;
    *(uint4*)&Vs[sr + 32][sc * 8] = pv1;
    {
      long ko = (long)(kt + 1) * 64;
      pk0 = *(const uint4*)(KgS + ko * 1536);
      pk1 = *(const uint4*)(KgS + (ko + 32) * 1536);
      bool vok = (ko + sc * 8) < NSEQ;
      pv0 = vok ? *(const uint4*)(VgS + ko) : z4;
      pv1 = vok ? *(const uint4*)(VgS + (long)32 * 1800 + ko) : z4;
    }
    __syncthreads();
    ATTN_TILE_BODY(false)
  }
  {                                          // tile 28: mask keys >= 1800
    __syncthreads();
    *(uint4*)&Ks[sr][sc * 8]      = pk0;
    *(uint4*)&Ks[sr + 32][sc * 8] = pk1;
    *(uint4*)&Vs[sr][sc * 8]      = pv0;
    *(uint4*)&Vs[sr + 32][sc * 8] = pv1;
    __syncthreads();
    ATTN_TILE_BODY(true)
  }

#pragma unroll
  for (int mk = 1; mk < 16; mk <<= 1)
#pragma unroll
    for (int r = 0; r < 4; ++r) {
      lsA[r] += __shfl_xor(lsA[r], mk);
      lsB[r] += __shfl_xor(lsB[r], mk);
    }

#pragma unroll
  for (int r = 0; r < 4; ++r) {
    int qgA = q0 + wave * 32 + quad * 4 + r;
    if (qgA < NSEQ) {
      float inv = 1.f / lsA[r];
#pragma unroll
      for (int nt = 0; nt < 4; ++nt)
        out[(baseBN + qgA) * 512 + hh * 64 + nt * 16 + l16] = (f16)(oA[nt][r] * inv);
    }
    int qgB = qgA + 16;
    if (qgB < NSEQ) {
      float inv = 1.f / lsB[r];
#pragma unroll
      for (int nt = 0; nt < 4; ++nt)
        out[(baseBN + qgB) * 512 + hh * 64 + nt * 16 + l16] = (f16)(oB[nt][r] * inv);
    }
  }
}

// ---------------- head: 225 blocks x 32 rows, Wt in registers, 6 atomics/block ----------------
__global__ __launch_bounds__(192)
void head_kernel(const float* __restrict__ x, const float* __restrict__ patches,
                 const int* __restrict__ mi, const float* __restrict__ Wt,
                 const float* __restrict__ bt, float* __restrict__ lossAcc) {
  int t = threadIdx.x;            // 192 = 6 pd * 32 lanes
  int pd = t / 32, sg = t % 32;
  float wt[16];
#pragma unroll
  for (int k = 0; k < 16; ++k) wt[k] = Wt[(sg * 16 + k) * 6 + pd];
  float btv = bt[pd];
  float accAll = 0.f;
  for (int rr = 0; rr < 32; ++rr) {
    int bi = blockIdx.x * 32 + rr;    // 0..7199
    int b = bi / NMASK;
    int idx = mi[bi];
    const float4* xr4 = (const float4*)(x + ((long)b * NSEQ + idx) * DIM);
    float acc = 0.f;
#pragma unroll
    for (int j = 0; j < 4; ++j) {
      float4 xa = xr4[sg * 4 + j];
      acc += xa.x * wt[j * 4] + xa.y * wt[j * 4 + 1] + xa.z * wt[j * 4 + 2] + xa.w * wt[j * 4 + 3];
    }
#pragma unroll
    for (int mk = 1; mk < 32; mk <<= 1) acc += __shfl_xor(acc, mk);
    if (sg == 0) {
      float pred = acc + btv;
      accAll += fabsf(pred - patches[((long)b * NSEQ + idx) * 6 + pd]);
    }
  }
  if (sg == 0) atomicAdd(lossAcc, accAll);
}

__global__ void finalize_kernel(const float* __restrict__ acc, float* __restrict__ out) {
  if (threadIdx.x == 0 && blockIdx.x == 0)
    out[0] = acc[0] * (1.0f / 38880000.0f);   // /(8*900*6) / 900
}

// ---------------- launcher ----------------
extern "C" void kernel_launch(void* const* d_in, const int* in_sizes, int n_in,
                              void* d_out, int out_size, void* d_ws, size_t ws_size,
                              hipStream_t stream) {
  (void)in_sizes; (void)n_in; (void)out_size; (void)ws_size;
  const float* img       = (const float*)d_in[0];
  const float* pos_table = (const float*)d_in[1];
  const float* val_table = (const float*)d_in[2];
  const float* patch_W   = (const float*)d_in[3];
  const float* patch_b   = (const float*)d_in[4];
  const float* mask_tok  = (const float*)d_in[5];
  const float* ln1_s     = (const float*)d_in[6];
  const float* ln1_b     = (const float*)d_in[7];
  const float* Wqkv      = (const float*)d_in[8];
  const float* bqkv      = (const float*)d_in[9];
  const float* Wo        = (const float*)d_in[10];
  const float* bo        = (const float*)d_in[11];
  const float* ln2_s     = (const float*)d_in[12];
  const float* ln2_b     = (const float*)d_in[13];
  const float* W1        = (const float*)d_in[14];
  const float* b1        = (const float*)d_in[15];
  const float* W2        = (const float*)d_in[16];
  const float* b2        = (const float*)d_in[17];
  const float* Wt        = (const float*)d_in[18];
  const float* bt        = (const float*)d_in[19];
  const int* valid_len   = (const int*)d_in[20];
  const int* mask_idx    = (const int*)d_in[21];

  char* p = (char*)d_ws;
  auto alloc = [&](size_t bytes) { char* r = p; p += (bytes + 511) & ~(size_t)511; return r; };
  float* patches = (float*)alloc((size_t)MROWS * 6 * 4);
  int*   maskf   = (int*)alloc((size_t)MROWS * 4);
  float* lossAcc = (float*)alloc(256);
  float* x       = (float*)alloc((size_t)MROWS * 512 * 4);
  f16*   h       = (f16*)alloc((size_t)MROWS * 512 * 2 + 512); // doubles as Vt
  f16*   qkv     = (f16*)alloc((size_t)MROWS * 2048 * 2);      // shared: qkv (1536) / mlp-hidden (2048)
  f16*   attn    = (f16*)alloc((size_t)MROWS * 512 * 2);
  f16*   WqT     = (f16*)alloc((size_t)4 * 1536 * 512 * 2);
  f16*   WoT     = (f16*)alloc((size_t)4 * 512 * 512 * 2);
  f16*   W1T     = (f16*)alloc((size_t)4 * 2048 * 512 * 2);
  f16*   W2T     = (f16*)alloc((size_t)4 * 512 * 2048 * 2);
  f16*   hid     = qkv;
  f16*   Vt      = h;   // h is dead between the QKV GEMM and ln2

  hipMemsetAsync(maskf, 0, (size_t)MROWS * 4, stream);
  hipMemsetAsync(lossAcc, 0, 4, stream);
  scatter_mask<<<29, 256, 0, stream>>>(mask_idx, maskf);

  transposeW<<<dim3(48, 16, 4), dim3(32, 8), 0, stream>>>(Wqkv, WqT, 512, 1536);
  transposeW<<<dim3(16, 16, 4), dim3(32, 8), 0, stream>>>(Wo,  WoT, 512, 512);
  transposeW<<<dim3(64, 16, 4), dim3(32, 8), 0, stream>>>(W1,  W1T, 512, 2048);
  transposeW<<<dim3(16, 64, 4), dim3(32, 8), 0, stream>>>(W2,  W2T, 2048, 512);

  prep_kernel<<<dim3(1800, 8), 256, 0, stream>>>(img, pos_table, val_table, patch_W, patch_b,
                                                 mask_tok, valid_len, maskf, patches, x);

  for (int l = 0; l < 4; ++l) {
    ln_kernel<<<MROWS, 256, 0, stream>>>(x, ln1_s + l * 512, ln1_b + l * 512, h);
    gemm_kernel<0><<<dim3(12, 113), 256, 0, stream>>>(h, WqT + (size_t)l * 1536 * 512,
                                                      bqkv + l * 1536, nullptr, nullptr, qkv,
                                                      MROWS, 1536, 512);
    transposeV<<<dim3(29, 64), 256, 0, stream>>>(qkv, Vt);
    attn_kernel<<<dim3(960), 256, 0, stream>>>(qkv, Vt, attn);
    gemm_kernel<1><<<dim3(4, 113), 256, 0, stream>>>(attn, WoT + (size_t)l * 512 * 512,
                                                     bo + l * 512, x, x, nullptr,
                                                     MROWS, 512, 512);
    ln_kernel<<<MROWS, 256, 0, stream>>>(x, ln2_s + l * 512, ln2_b + l * 512, h);
    gemm_kernel<2><<<dim3(16, 113), 256, 0, stream>>>(h, W1T + (size_t)l * 2048 * 512,
                                                      b1 + l * 2048, nullptr, nullptr, hid,
                                                      MROWS, 2048, 512);
    gemm_kernel<1><<<dim3(4, 113), 256, 0, stream>>>(hid, W2T + (size_t)l * 512 * 2048,
                                                     b2 + l * 512, x, x, nullptr,
                                                     MROWS, 512, 2048);
  }

  head_kernel<<<225, 192, 0, stream>>>(x, patches, mask_idx, Wt, bt, lossAcc);
  finalize_kernel<<<1, 64, 0, stream>>>(lossAcc, (float*)d_out);
}

// Round 11
// 1500.928 us; speedup vs baseline: 1.8397x; 1.1945x over previous
//
#include <hip/hip_runtime.h>
#include <hip/hip_fp8.h>
#include <cstdint>

typedef _Float16 f16;
typedef _Float16 f16x4 __attribute__((ext_vector_type(4)));
typedef _Float16 f16x8 __attribute__((ext_vector_type(8)));
typedef float    f32x4 __attribute__((ext_vector_type(4)));
typedef __hip_fp8_e4m3 fp8;
typedef long     i64;
typedef unsigned char u8;

#define BATCH 8
#define NSEQ  1800
#define DIM   512
#define NMASK 900
#define MROWS 14400   // BATCH*NSEQ

// ---------------- async 16B global->LDS (with fallback) ----------------
__device__ __forceinline__ void stage16(const void* g, void* lds_wave_base, int lane) {
#if __has_builtin(__builtin_amdgcn_global_load_lds)
  (void)lane;
  __builtin_amdgcn_global_load_lds((const __attribute__((address_space(1))) void*)g,
                                   (__attribute__((address_space(3))) void*)lds_wave_base,
                                   16, 0, 0);
#else
  ((uint4*)lds_wave_base)[lane] = *(const uint4*)g;
#endif
}

__device__ __forceinline__ float gelu_f(float x) {
  // tanh-approx gelu (jax.nn.gelu approximate=True)
  float x3 = x * x * x;
  float y  = 0.7978845608028654f * (x + 0.044715f * x3);
  float t;
  if (y > 15.f)       t = 1.f;
  else if (y < -15.f) t = -1.f;
  else { float e = __expf(2.f * y); t = (e - 1.f) / (e + 1.f); }
  return 0.5f * x * (1.f + t);
}

// ---------------- mask scatter ----------------
__global__ void scatter_mask(const int* __restrict__ mi, int* __restrict__ maskf) {
  int i = blockIdx.x * 256 + threadIdx.x;
  if (i < BATCH * NMASK) {
    int b = i / NMASK;
    maskf[b * NSEQ + mi[i]] = 1;
  }
}

// ---------------- weight transpose + fp8 convert: in[K,N] -> out[N,K] ----------------
__global__ void transposeW(const float* __restrict__ in, fp8* __restrict__ out, int K, int N) {
  long off = (long)blockIdx.z * K * N;
  const float* ip = in + off;
  fp8* op = out + off;
  __shared__ float tile[32][33];
  int n0 = blockIdx.x * 32, k0 = blockIdx.y * 32;
  int tx = threadIdx.x, ty = threadIdx.y;  // (32,8)
#pragma unroll
  for (int i = 0; i < 4; ++i)
    tile[ty + 8 * i][tx] = ip[(long)(k0 + ty + 8 * i) * N + n0 + tx];
  __syncthreads();
#pragma unroll
  for (int i = 0; i < 4; ++i)
    op[(long)(n0 + ty + 8 * i) * K + k0 + tx] = fp8(tile[tx][ty + 8 * i]);
}

// ---------------- V transpose per layer: qkv[:,1024:1536] -> Vt[(b*8+h)*64+dh][1800] ----------------
__global__ __launch_bounds__(256)
void transposeV(const f16* __restrict__ qkv, f16* __restrict__ Vt) {
  __shared__ f16 tl[64][72];
  const int kt = blockIdx.x, bh = blockIdx.y;     // (29, 64)
  const int b = bh >> 3, hh = bh & 7;
  const int k0 = kt * 64;
  const int t = threadIdx.x;
  const int r = t >> 3, c = t & 7;
  const f16* src = qkv + (long)b * NSEQ * 1536 + hh * 64 + 1024;
  int key0 = k0 + r;      if (key0 > NSEQ - 1) key0 = NSEQ - 1;
  int key1 = k0 + r + 32; if (key1 > NSEQ - 1) key1 = NSEQ - 1;
  *(uint4*)&tl[r][c * 8]      = *(const uint4*)(src + (long)key0 * 1536 + c * 8);
  *(uint4*)&tl[r + 32][c * 8] = *(const uint4*)(src + (long)key1 * 1536 + c * 8);
  __syncthreads();
  f16* dst = Vt + (long)bh * 64 * 1800;
  const int dh = t & 63;
#pragma unroll
  for (int it = 0; it < 2; ++it) {
    int kc = (t >> 6) + it * 4;        // 0..7
    if (k0 + kc * 8 < NSEQ) {          // 1800 % 8 == 0
      f16x8 v;
#pragma unroll
      for (int j = 0; j < 8; ++j) v[j] = tl[kc * 8 + j][dh];
      *(f16x8*)(dst + (long)dh * 1800 + k0 + kc * 8) = v;
    }
  }
}

// ---------------- patch embed + pos/val emb + mask token -> x0 ----------------
__global__ __launch_bounds__(256)
void prep_kernel(const float* __restrict__ img, const float* __restrict__ pos_table,
                 const float* __restrict__ val_table, const float* __restrict__ patch_W,
                 const float* __restrict__ patch_b, const float* __restrict__ mask_tok,
                 const int* __restrict__ valid_len, const int* __restrict__ maskf,
                 float* __restrict__ patches, float* __restrict__ x0) {
  int n = blockIdx.x;       // 0..1799
  int b = blockIdx.y;       // 0..7
  int t = threadIdx.x;
  __shared__ float p[6];
  int h = n / 75, ws = n % 75;
  if (t < 6) {
    int pp = t / 3, c = t % 3;
    float v = img[((b * 3 + c) * 24 + h) * 150 + ws * 2 + pp];
    p[t] = v;
    patches[((long)b * NSEQ + n) * 6 + t] = v;
  }
  __syncthreads();
  int vl = valid_len[b];
  if (vl == 150) vl = 149;
  int nv = (vl + 1) >> 1;          // ceil(vl/2)
  int seg = (ws < nv) ? 1 : 0;
  bool masked = maskf[b * NSEQ + n] != 0;
  for (int d = t; d < DIM; d += 256) {
    float pos = pos_table[(long)(n + 1) * DIM + d] + val_table[seg * DIM + d];
    float v;
    if (masked) {
      v = mask_tok[d] + pos;
    } else {
      float acc = patch_b[d] + pos;
#pragma unroll
      for (int j = 0; j < 6; ++j) acc += p[j] * patch_W[j * DIM + d];
      v = acc;
    }
    x0[((long)b * NSEQ + n) * DIM + d] = v;
  }
}

// ---------------- LayerNorm (fp32 in -> fp8 out) ----------------
__global__ __launch_bounds__(256)
void ln_kernel(const float* __restrict__ x, const float* __restrict__ s,
               const float* __restrict__ bb, fp8* __restrict__ out) {
  long row = blockIdx.x;
  const float* xr = x + row * DIM;
  int t = threadIdx.x;
  float v0 = xr[t], v1 = xr[t + 256];
  float sum = v0 + v1, sq = v0 * v0 + v1 * v1;
#pragma unroll
  for (int mk = 1; mk < 64; mk <<= 1) {
    sum += __shfl_xor(sum, mk);
    sq  += __shfl_xor(sq, mk);
  }
  __shared__ float red[8];
  int wave = t >> 6, lane = t & 63;
  if (lane == 0) { red[wave] = sum; red[wave + 4] = sq; }
  __syncthreads();
  sum = red[0] + red[1] + red[2] + red[3];
  sq  = red[4] + red[5] + red[6] + red[7];
  float mean = sum * (1.f / DIM);
  float var  = sq * (1.f / DIM) - mean * mean;
  float rstd = rsqrtf(var + 1e-5f);
  out[row * DIM + t]       = fp8((v0 - mean) * rstd * s[t] + bb[t]);
  out[row * DIM + t + 256] = fp8((v1 - mean) * rstd * s[t + 256] + bb[t + 256]);
}

// ---------------- MFMA fp8 GEMM: BK=128, swapped operands ----------------
// C[M,N] = A[M,K] @ Bt[N,K]^T, A/Bt fp8-e4m3. mfma(a=B-frag, b=A-frag) ->
// D[row=n][col=m]: 4 consecutive n/thread -> float4 / packed-4B stores.
// LDS layout: byte = c16*2048 + row*16 + b holds X[row][kt + c16*16 + b].
// Fragment (k = ks*32 + quad*8 + j): c16 = 2*ks + (quad>>1), off = (quad&1)*8.
// EPI 0: bias -> f16 out; 1: bias + residual -> f32; 2: bias + gelu -> fp8.
template <int EPI>
__global__ __launch_bounds__(256)
void gemm8_kernel(const u8* __restrict__ A, const u8* __restrict__ Bt,
                  const float* __restrict__ bias, const float* __restrict__ res,
                  float* __restrict__ outF, f16* __restrict__ outH, fp8* __restrict__ out8,
                  int M, int N, int K) {
  __shared__ u8 As[8 * 128 * 16];   // 16 KB
  __shared__ u8 Bs[8 * 128 * 16];   // 16 KB
  const int tid  = threadIdx.x;
  const int wave = tid >> 6, lane = tid & 63;
  const int quad = lane >> 4, l16 = lane & 15;
  const int wm = wave >> 1, wn = wave & 1;
  const long rowBase = (long)blockIdx.y * 128;
  const long colBase = (long)blockIdx.x * 128;

  f32x4 acc[4][4];   // [ni][mi]
  f32x4 zero = {0.f, 0.f, 0.f, 0.f};
#pragma unroll
  for (int ni = 0; ni < 4; ++ni)
#pragma unroll
    for (int mi = 0; mi < 4; ++mi) acc[ni][mi] = zero;

  long rA0 = rowBase + lane;       if (rA0 > M - 1) rA0 = M - 1;
  long rA1 = rowBase + 64 + lane;  if (rA1 > M - 1) rA1 = M - 1;
  const u8* Arow0 = A + rA0 * K + wave * 16;    // c16 = wave
  const u8* Arow1 = A + rA1 * K + wave * 16;
  const u8* Brow0 = Bt + (colBase + lane) * K + wave * 16;
  const u8* Brow1 = Bt + (colBase + 64 + lane) * K + wave * 16;
  u8* AsC0 = As + wave * 2048;              // c16=wave,   rows 0-63
  u8* AsC1 = AsC0 + 64 * 16;                // c16=wave,   rows 64-127
  u8* AsC2 = As + (wave + 4) * 2048;        // c16=wave+4  (k-offset +64)
  u8* AsC3 = AsC2 + 64 * 16;
  u8* BsC0 = Bs + wave * 2048;
  u8* BsC1 = BsC0 + 64 * 16;
  u8* BsC2 = Bs + (wave + 4) * 2048;
  u8* BsC3 = BsC2 + 64 * 16;

  for (int kt = 0; kt < K; kt += 128) {
    __syncthreads();
    stage16(Arow0 + kt,      AsC0, lane);
    stage16(Arow1 + kt,      AsC1, lane);
    stage16(Arow0 + kt + 64, AsC2, lane);
    stage16(Arow1 + kt + 64, AsC3, lane);
    stage16(Brow0 + kt,      BsC0, lane);
    stage16(Brow1 + kt,      BsC1, lane);
    stage16(Brow0 + kt + 64, BsC2, lane);
    stage16(Brow1 + kt + 64, BsC3, lane);
    __syncthreads();
#pragma unroll
    for (int ks = 0; ks < 4; ++ks) {
      const int cb = (2 * ks + (quad >> 1)) * 2048 + (quad & 1) * 8;
      i64 af[4], bf[4];
#pragma unroll
      for (int mi = 0; mi < 4; ++mi)
        af[mi] = *(const i64*)&As[cb + (wm * 64 + mi * 16 + l16) * 16];
#pragma unroll
      for (int ni = 0; ni < 4; ++ni)
        bf[ni] = *(const i64*)&Bs[cb + (wn * 64 + ni * 16 + l16) * 16];
#pragma unroll
      for (int ni = 0; ni < 4; ++ni)
#pragma unroll
        for (int mi = 0; mi < 4; ++mi)
          acc[ni][mi] = __builtin_amdgcn_mfma_f32_16x16x32_fp8_fp8(bf[ni], af[mi], acc[ni][mi], 0, 0, 0);
    }
  }

  // epilogue: m = rowBase + wm*64 + mi*16 + l16 ; n = colBase + wn*64 + ni*16 + quad*4 + r
#pragma unroll
  for (int mi = 0; mi < 4; ++mi) {
    long m = rowBase + wm * 64 + mi * 16 + l16;
    if (m < M) {
#pragma unroll
      for (int ni = 0; ni < 4; ++ni) {
        long n = colBase + wn * 64 + ni * 16 + quad * 4;
        float4 bv = *(const float4*)&bias[n];
        f32x4 v = acc[ni][mi];
        v[0] += bv.x; v[1] += bv.y; v[2] += bv.z; v[3] += bv.w;
        long o = m * N + n;
        if (EPI == 1) {
          float4 rr = *(const float4*)&res[o];
          float4 ov = {v[0] + rr.x, v[1] + rr.y, v[2] + rr.z, v[3] + rr.w};
          *(float4*)&outF[o] = ov;
        } else if (EPI == 2) {
          fp8 hv[4];
#pragma unroll
          for (int r = 0; r < 4; ++r) hv[r] = fp8(gelu_f(v[r]));
          *(uint32_t*)&out8[o] = *(const uint32_t*)hv;
        } else {
          f16x4 hv;
#pragma unroll
          for (int r = 0; r < 4; ++r) hv[r] = (f16)v[r];
          *(f16x4*)&outH[o] = hv;
        }
      }
    }
  }
}

// ---------------- MFMA flash attention v6b (R10 known-good; epilogue -> fp8) ----------------
#define ATTN_TILE_BODY(MASKV)                                                           \
  {                                                                                     \
    _Pragma("unroll")                                                                   \
    for (int n = 0; n < 4; ++n) {                                                       \
      f16x8 b0 = *(const f16x8*)&Ks[n * 16 + l16][quad * 8];                            \
      f16x8 b1 = *(const f16x8*)&Ks[n * 16 + l16][32 + quad * 8];                       \
      f32x4 zz = {0.f, 0.f, 0.f, 0.f};                                                  \
      zz = __builtin_amdgcn_mfma_f32_16x16x32_f16(qfA0, b0, zz, 0, 0, 0);               \
      zz = __builtin_amdgcn_mfma_f32_16x16x32_f16(qfA1, b1, zz, 0, 0, 0);               \
      bool bad = (MASKV) && (n > 0 || l16 >= 8);                                        \
      _Pragma("unroll")                                                                 \
      for (int r = 0; r < 4; ++r) {                                                     \
        float pp = exp2f(fmaf(zz[r], K1, -8.f));                                        \
        if (bad) pp = 0.f;                                                              \
        Ps[wave * 16 + quad * 4 + r][n * 16 + l16] = (f16)pp;                           \
        lsA[r] += pp;                                                                   \
      }                                                                                 \
    }                                                                                   \
    {                                                                                   \
      f16x8 pa0 = *(const f16x8*)&Ps[wave * 16 + l16][quad * 8];                        \
      f16x8 pa1 = *(const f16x8*)&Ps[wave * 16 + l16][32 + quad * 8];                   \
      _Pragma("unroll")                                                                 \
      for (int nt = 0; nt < 4; ++nt) {                                                  \
        f16x8 vb0 = *(const f16x8*)&Vs[nt * 16 + l16][quad * 8];                        \
        f16x8 vb1 = *(const f16x8*)&Vs[nt * 16 + l16][32 + quad * 8];                   \
        oA[nt] = __builtin_amdgcn_mfma_f32_16x16x32_f16(pa0, vb0, oA[nt], 0, 0, 0);     \
        oA[nt] = __builtin_amdgcn_mfma_f32_16x16x32_f16(pa1, vb1, oA[nt], 0, 0, 0);     \
      }                                                                                 \
    }                                                                                   \
    _Pragma("unroll")                                                                   \
    for (int n = 0; n < 4; ++n) {                                                       \
      f16x8 b0 = *(const f16x8*)&Ks[n * 16 + l16][quad * 8];                            \
      f16x8 b1 = *(const f16x8*)&Ks[n * 16 + l16][32 + quad * 8];                       \
      f32x4 zz = {0.f, 0.f, 0.f, 0.f};                                                  \
      zz = __builtin_amdgcn_mfma_f32_16x16x32_f16(qfB0, b0, zz, 0, 0, 0);               \
      zz = __builtin_amdgcn_mfma_f32_16x16x32_f16(qfB1, b1, zz, 0, 0, 0);               \
      bool bad = (MASKV) && (n > 0 || l16 >= 8);                                        \
      _Pragma("unroll")                                                                 \
      for (int r = 0; r < 4; ++r) {                                                     \
        float pp = exp2f(fmaf(zz[r], K1, -8.f));                                        \
        if (bad) pp = 0.f;                                                              \
        Ps[wave * 16 + quad * 4 + r][n * 16 + l16] = (f16)pp;                           \
        lsB[r] += pp;                                                                   \
      }                                                                                 \
    }                                                                                   \
    {                                                                                   \
      f16x8 pa0 = *(const f16x8*)&Ps[wave * 16 + l16][quad * 8];                        \
      f16x8 pa1 = *(const f16x8*)&Ps[wave * 16 + l16][32 + quad * 8];                   \
      _Pragma("unroll")                                                                 \
      for (int nt = 0; nt < 4; ++nt) {                                                  \
        f16x8 vb0 = *(const f16x8*)&Vs[nt * 16 + l16][quad * 8];                        \
        f16x8 vb1 = *(const f16x8*)&Vs[nt * 16 + l16][32 + quad * 8];                   \
        oB[nt] = __builtin_amdgcn_mfma_f32_16x16x32_f16(pa0, vb0, oB[nt], 0, 0, 0);     \
        oB[nt] = __builtin_amdgcn_mfma_f32_16x16x32_f16(pa1, vb1, oB[nt], 0, 0, 0);     \
      }                                                                                 \
    }                                                                                   \
  }

__global__ __launch_bounds__(256, 4)
void attn_kernel(const f16* __restrict__ qkv, const f16* __restrict__ Vt,
                 fp8* __restrict__ out) {
  const int g = blockIdx.x;                  // 0..959
  const int hi = g / 120, rem = g % 120;     // 120 = 15 q-tiles * 8
  const int qt = rem >> 3;                   // 0..14
  const int bh = hi * 8 + (rem & 7);         // g%8 == bh&7 -> one XCD per bh
  const int b = bh >> 3, hh = bh & 7;
  const int t = threadIdx.x;
  const int wave = t >> 6, lane = t & 63;
  const int quad = lane >> 4, l16 = lane & 15;
  const int q0 = qt * 128;
  const long baseBN = (long)b * NSEQ;
  const float K1 = 0.18033688011112042f;     // 0.125 * log2(e)

  __shared__ f16 Ks[64][80];   // [key][dh]
  __shared__ f16 Vs[64][80];   // [dh][key]
  __shared__ f16 Ps[64][80];   // [q%64][key], rows wave-private, reused A->B

  int qrA = q0 + wave * 32 + l16;      if (qrA > NSEQ - 1) qrA = NSEQ - 1;
  int qrB = q0 + wave * 32 + 16 + l16; if (qrB > NSEQ - 1) qrB = NSEQ - 1;
  const f16* QpA = qkv + (baseBN + qrA) * 1536 + hh * 64 + quad * 8;
  const f16* QpB = qkv + (baseBN + qrB) * 1536 + hh * 64 + quad * 8;
  f16x8 qfA0 = *(const f16x8*)(QpA);
  f16x8 qfA1 = *(const f16x8*)(QpA + 32);
  f16x8 qfB0 = *(const f16x8*)(QpB);
  f16x8 qfB1 = *(const f16x8*)(QpB + 32);

  f32x4 oA[4], oB[4];
  float lsA[4] = {0.f, 0.f, 0.f, 0.f}, lsB[4] = {0.f, 0.f, 0.f, 0.f};
#pragma unroll
  for (int nt = 0; nt < 4; ++nt) { oA[nt] = f32x4{0,0,0,0}; oB[nt] = f32x4{0,0,0,0}; }

  const f16* Kg = qkv + baseBN * 1536 + hh * 64 + 512;
  const f16* Vg = Vt + (long)bh * 64 * 1800;
  const int sr = t >> 3, sc = t & 7;
  const uint4 z4 = {0u, 0u, 0u, 0u};

  const f16* KgS = Kg + (long)sr * 1536 + sc * 8;
  const f16* VgS = Vg + (long)sr * 1800 + sc * 8;

  uint4 pk0 = *(const uint4*)(KgS);
  uint4 pk1 = *(const uint4*)(KgS + (long)32 * 1536);
  uint4 pv0 = *(const uint4*)(VgS);
  uint4 pv1 = *(const uint4*)(VgS + (long)32 * 1800);

  for (int kt = 0; kt < 28; ++kt) {          // tiles 0..27: no key masking
    __syncthreads();
    *(uint4*)&Ks[sr][sc * 8]      = pk0;
    *(uint4*)&Ks[sr + 32][sc * 8] = pk1;
    *(uint4*)&Vs[sr][sc * 8]      = pv0;
    *(uint4*)&Vs[sr + 32][sc * 8] = pv1;
    {
      long ko = (long)(kt + 1) * 64;
      pk0 = *(const uint4*)(KgS + ko * 1536);
      pk1 = *(const uint4*)(KgS + (ko + 32) * 1536);
      bool vok = (ko + sc * 8) < NSEQ;
      pv0 = vok ? *(const uint4*)(VgS + ko) : z4;
      pv1 = vok ? *(const uint4*)(VgS + (long)32 * 1800 + ko) : z4;
    }
    __syncthreads();
    ATTN_TILE_BODY(false)
  }
  {                                          // tile 28: mask keys >= 1800
    __syncthreads();
    *(uint4*)&Ks[sr][sc * 8]      = pk0;
    *(uint4*)&Ks[sr + 32][sc * 8] = pk1;
    *(uint4*)&Vs[sr][sc * 8]      = pv0;
    *(uint4*)&Vs[sr + 32][sc * 8] = pv1;
    __syncthreads();
    ATTN_TILE_BODY(true)
  }

#pragma unroll
  for (int mk = 1; mk < 16; mk <<= 1)
#pragma unroll
    for (int r = 0; r < 4; ++r) {
      lsA[r] += __shfl_xor(lsA[r], mk);
      lsB[r] += __shfl_xor(lsB[r], mk);
    }

#pragma unroll
  for (int r = 0; r < 4; ++r) {
    int qgA = q0 + wave * 32 + quad * 4 + r;
    if (qgA < NSEQ) {
      float inv = 1.f / lsA[r];
#pragma unroll
      for (int nt = 0; nt < 4; ++nt)
        out[(baseBN + qgA) * 512 + hh * 64 + nt * 16 + l16] = fp8(oA[nt][r] * inv);
    }
    int qgB = qgA + 16;
    if (qgB < NSEQ) {
      float inv = 1.f / lsB[r];
#pragma unroll
      for (int nt = 0; nt < 4; ++nt)
        out[(baseBN + qgB) * 512 + hh * 64 + nt * 16 + l16] = fp8(oB[nt][r] * inv);
    }
  }
}

// ---------------- head: 225 blocks x 32 rows, Wt in registers, 6 atomics/block ----------------
__global__ __launch_bounds__(192)
void head_kernel(const float* __restrict__ x, const float* __restrict__ patches,
                 const int* __restrict__ mi, const float* __restrict__ Wt,
                 const float* __restrict__ bt, float* __restrict__ lossAcc) {
  int t = threadIdx.x;            // 192 = 6 pd * 32 lanes
  int pd = t / 32, sg = t % 32;
  float wt[16];
#pragma unroll
  for (int k = 0; k < 16; ++k) wt[k] = Wt[(sg * 16 + k) * 6 + pd];
  float btv = bt[pd];
  float accAll = 0.f;
  for (int rr = 0; rr < 32; ++rr) {
    int bi = blockIdx.x * 32 + rr;    // 0..7199
    int b = bi / NMASK;
    int idx = mi[bi];
    const float4* xr4 = (const float4*)(x + ((long)b * NSEQ + idx) * DIM);
    float acc = 0.f;
#pragma unroll
    for (int j = 0; j < 4; ++j) {
      float4 xa = xr4[sg * 4 + j];
      acc += xa.x * wt[j * 4] + xa.y * wt[j * 4 + 1] + xa.z * wt[j * 4 + 2] + xa.w * wt[j * 4 + 3];
    }
#pragma unroll
    for (int mk = 1; mk < 32; mk <<= 1) acc += __shfl_xor(acc, mk);
    if (sg == 0) {
      float pred = acc + btv;
      accAll += fabsf(pred - patches[((long)b * NSEQ + idx) * 6 + pd]);
    }
  }
  if (sg == 0) atomicAdd(lossAcc, accAll);
}

__global__ void finalize_kernel(const float* __restrict__ acc, float* __restrict__ out) {
  if (threadIdx.x == 0 && blockIdx.x == 0)
    out[0] = acc[0] * (1.0f / 38880000.0f);   // /(8*900*6) / 900
}

// ---------------- launcher ----------------
extern "C" void kernel_launch(void* const* d_in, const int* in_sizes, int n_in,
                              void* d_out, int out_size, void* d_ws, size_t ws_size,
                              hipStream_t stream) {
  (void)in_sizes; (void)n_in; (void)out_size; (void)ws_size;
  const float* img       = (const float*)d_in[0];
  const float* pos_table = (const float*)d_in[1];
  const float* val_table = (const float*)d_in[2];
  const float* patch_W   = (const float*)d_in[3];
  const float* patch_b   = (const float*)d_in[4];
  const float* mask_tok  = (const float*)d_in[5];
  const float* ln1_s     = (const float*)d_in[6];
  const float* ln1_b     = (const float*)d_in[7];
  const float* Wqkv      = (const float*)d_in[8];
  const float* bqkv      = (const float*)d_in[9];
  const float* Wo        = (const float*)d_in[10];
  const float* bo        = (const float*)d_in[11];
  const float* ln2_s     = (const float*)d_in[12];
  const float* ln2_b     = (const float*)d_in[13];
  const float* W1        = (const float*)d_in[14];
  const float* b1        = (const float*)d_in[15];
  const float* W2        = (const float*)d_in[16];
  const float* b2        = (const float*)d_in[17];
  const float* Wt        = (const float*)d_in[18];
  const float* bt        = (const float*)d_in[19];
  const int* valid_len   = (const int*)d_in[20];
  const int* mask_idx    = (const int*)d_in[21];

  char* p = (char*)d_ws;
  auto alloc = [&](size_t bytes) { char* r = p; p += (bytes + 511) & ~(size_t)511; return r; };
  float* patches = (float*)alloc((size_t)MROWS * 6 * 4);
  int*   maskf   = (int*)alloc((size_t)MROWS * 4);
  float* lossAcc = (float*)alloc(256);
  float* x       = (float*)alloc((size_t)MROWS * 512 * 4);
  char*  hbuf    = alloc((size_t)MROWS * 512 * 2 + 512);  // h (fp8) / Vt (f16) share
  f16*   qkv     = (f16*)alloc((size_t)MROWS * 2048 * 2); // qkv f16 (1536) / hid fp8 (2048)
  fp8*   attn    = (fp8*)alloc((size_t)MROWS * 512);
  fp8*   WqT     = (fp8*)alloc((size_t)4 * 1536 * 512);
  fp8*   WoT     = (fp8*)alloc((size_t)4 * 512 * 512);
  fp8*   W1T     = (fp8*)alloc((size_t)4 * 2048 * 512);
  fp8*   W2T     = (fp8*)alloc((size_t)4 * 512 * 2048);
  fp8*   h       = (fp8*)hbuf;
  f16*   Vt      = (f16*)hbuf;   // h dead between QKV GEMM and ln2
  fp8*   hid     = (fp8*)qkv;    // qkv dead after attn within a layer

  hipMemsetAsync(maskf, 0, (size_t)MROWS * 4, stream);
  hipMemsetAsync(lossAcc, 0, 4, stream);
  scatter_mask<<<29, 256, 0, stream>>>(mask_idx, maskf);

  transposeW<<<dim3(48, 16, 4), dim3(32, 8), 0, stream>>>(Wqkv, WqT, 512, 1536);
  transposeW<<<dim3(16, 16, 4), dim3(32, 8), 0, stream>>>(Wo,  WoT, 512, 512);
  transposeW<<<dim3(64, 16, 4), dim3(32, 8), 0, stream>>>(W1,  W1T, 512, 2048);
  transposeW<<<dim3(16, 64, 4), dim3(32, 8), 0, stream>>>(W2,  W2T, 2048, 512);

  prep_kernel<<<dim3(1800, 8), 256, 0, stream>>>(img, pos_table, val_table, patch_W, patch_b,
                                                 mask_tok, valid_len, maskf, patches, x);

  for (int l = 0; l < 4; ++l) {
    ln_kernel<<<MROWS, 256, 0, stream>>>(x, ln1_s + l * 512, ln1_b + l * 512, h);
    gemm8_kernel<0><<<dim3(12, 113), 256, 0, stream>>>((const u8*)h, (const u8*)(WqT + (size_t)l * 1536 * 512),
                                                       bqkv + l * 1536, nullptr, nullptr, qkv, nullptr,
                                                       MROWS, 1536, 512);
    transposeV<<<dim3(29, 64), 256, 0, stream>>>(qkv, Vt);
    attn_kernel<<<dim3(960), 256, 0, stream>>>(qkv, Vt, attn);
    gemm8_kernel<1><<<dim3(4, 113), 256, 0, stream>>>((const u8*)attn, (const u8*)(WoT + (size_t)l * 512 * 512),
                                                      bo + l * 512, x, x, nullptr, nullptr,
                                                      MROWS, 512, 512);
    ln_kernel<<<MROWS, 256, 0, stream>>>(x, ln2_s + l * 512, ln2_b + l * 512, h);
    gemm8_kernel<2><<<dim3(16, 113), 256, 0, stream>>>((const u8*)h, (const u8*)(W1T + (size_t)l * 2048 * 512),
                                                       b1 + l * 2048, nullptr, nullptr, nullptr, hid,
                                                       MROWS, 2048, 512);
    gemm8_kernel<1><<<dim3(4, 113), 256, 0, stream>>>((const u8*)hid, (const u8*)(W2T + (size_t)l * 512 * 2048),
                                                      b2 + l * 512, x, x, nullptr, nullptr,
                                                      MROWS, 512, 2048);
  }

  head_kernel<<<225, 192, 0, stream>>>(x, patches, mask_idx, Wt, bt, lossAcc);
  finalize_kernel<<<1, 64, 0, stream>>>(lossAcc, (float*)d_out);
}